// Round 11
// baseline (241.586 us; speedup 1.0000x reference)
//
#include <hip/hip_runtime.h>

#define N_NODES 100000
#define N_EDGES 1250000
#define D_IN 64
#define D_H 64
#define D_OUT 32

#define BUCKETS 391            // ceil(100000 / 256)
#define GRP 256                // nodes per bucket (dst >> 8)
#define PREP_NB 512            // blocks in k_prep
#define PREP_CH 2442           // ceil(N_EDGES / PREP_NB) edges per block
#define SCAP 32                // slack slots per (block,bucket); mean 6.25, +10 sigma
#define BSTRIDE (PREP_NB*SCAP) // ints per bucket region in ebuf = 16384
#define CSRCAP 4096            // csr slots per bucket; mean 3200, +15 sigma (fixed graph)

typedef __attribute__((ext_vector_type(8))) short bf16x8;
typedef __attribute__((ext_vector_type(4))) float f32x4;

__device__ __forceinline__ unsigned short f2bf(float f) {
    unsigned u = __float_as_uint(f);
    u = (u + 0x7fffu + ((u >> 16) & 1u)) >> 16;   // RNE
    return (unsigned short)u;
}
__device__ __forceinline__ float bfhi(unsigned v) { return __uint_as_float(v & 0xffff0000u); }
__device__ __forceinline__ float bflo(unsigned v) { return __uint_as_float(v << 16); }

// ---------------------------------------------------------------------------
// 5-dispatch pipeline. R10 lessons: every kernel is in the 20-40us band;
// phb had a 196-block tail (3/4 of chip idle) -> GRP 256 / 391 blocks;
// hr goes bf16 (saves 13MB r+w); producer stores are nontemporal so the
// gather working set (xh / hWlh) keeps the L2 to itself.
// ---------------------------------------------------------------------------

__global__ __launch_bounds__(256) void k_prep(const float* __restrict__ x,
                                              unsigned short* __restrict__ xh,
                                              const int* __restrict__ src,
                                              const int* __restrict__ dst,
                                              int* __restrict__ ebuf,
                                              int* __restrict__ pcnt) {
    __shared__ int ofs[BUCKETS];
    int t = threadIdx.x, b = blockIdx.x;
    for (int i = t; i < BUCKETS; i += 256) ofs[i] = 0;
    __syncthreads();

    const int TOT = N_NODES * 64 / 4;
    for (int i = b * 256 + t; i < TOT; i += PREP_NB * 256) {
        float4 v = *(const float4*)(x + (size_t)i * 4);
        unsigned lo = (unsigned)f2bf(v.x) | ((unsigned)f2bf(v.y) << 16);
        unsigned hi = (unsigned)f2bf(v.z) | ((unsigned)f2bf(v.w) << 16);
        unsigned long long p = (unsigned long long)lo | ((unsigned long long)hi << 32);
        __builtin_nontemporal_store(p, (unsigned long long*)(xh + (size_t)i * 4));
    }

    int e0 = b * PREP_CH;
    int e1 = e0 + PREP_CH; if (e1 > N_EDGES) e1 = N_EDGES;
    for (int e = e0 + t; e < e1; e += 256) {
        int s = src[e], d = dst[e];
        if ((unsigned)d >= N_NODES) continue;
        int sv = ((unsigned)s < N_NODES) ? s : 0;
        int bk = d >> 8;
        int r = atomicAdd(&ofs[bk], 1);
        if (r < SCAP)
            __builtin_nontemporal_store(((d & 255) << 17) | sv,
                                        &ebuf[bk * BSTRIDE + b * SCAP + r]);
    }
    __syncthreads();
    for (int i = t; i < BUCKETS; i += 256) {
        int v = ofs[i]; if (v > SCAP) v = SCAP;
        pcnt[b * BUCKETS + i] = v;        // [blk][bucket]: coalesced writes
    }
}

// One block per bucket (391 blocks). rd[node] = (rstart, deg) packed.
__global__ __launch_bounds__(256) void k_phb(const int* __restrict__ ebuf,
                                             const int* __restrict__ pcnt,
                                             int2* __restrict__ rd,
                                             int* __restrict__ csr_src) {
    __shared__ int sedge[CSRCAP];   // 16 KB
    __shared__ int cnt[GRP];        // node hist / cursors
    __shared__ int part[256];
    int b = blockIdx.x, t = threadIdx.x;

    // scan the 512 per-source-block counts for this bucket (2 per thread)
    int c0 = pcnt[(2 * t) * BUCKETS + b];
    int c1 = pcnt[(2 * t + 1) * BUCKETS + b];
    int s = c0 + c1;
    part[t] = s;
    cnt[t] = 0;
    __syncthreads();
    for (int off = 1; off < 256; off <<= 1) {
        int u = (t >= off) ? part[t - off] : 0;
        __syncthreads();
        part[t] += u;
        __syncthreads();
    }
    int run = part[t] - s;
    {
        const int* sp = ebuf + b * BSTRIDE + (2 * t) * SCAP;
        int base = run;
        for (int j = 0; j < c0; ++j) if (base + j < CSRCAP) sedge[base + j] = sp[j];
        sp += SCAP;
        base = run + c0;
        for (int j = 0; j < c1; ++j) if (base + j < CSRCAP) sedge[base + j] = sp[j];
    }
    int n = part[255]; if (n > CSRCAP) n = CSRCAP;
    __syncthreads();
    for (int i = t; i < n; i += 256) atomicAdd(&cnt[sedge[i] >> 17], 1);
    __syncthreads();
    int d0 = cnt[t];            // this thread's node count (1 node per thread)
    part[t] = d0;
    __syncthreads();
    for (int off = 1; off < 256; off <<= 1) {
        int u = (t >= off) ? part[t - off] : 0;
        __syncthreads();
        part[t] += u;
        __syncthreads();
    }
    int g0 = b * CSRCAP + part[t] - d0;
    int node = b * GRP + t;
    if (node < N_NODES) rd[node] = make_int2(g0, d0);
    __syncthreads();
    cnt[t] = g0;
    __syncthreads();
    for (int i = t; i < n; i += 256) {
        int v = sedge[i];
        int pos = atomicAdd(&cnt[v >> 17], 1);
        __builtin_nontemporal_store(v & 0x1FFFF, &csr_src[pos]);
    }
}

// Half-wave per node (lanes c=0..31 cover the 128B bf16 row as bfloat162).
// 8 accumulator streams -> 16 row-loads in flight per wave.
__global__ __launch_bounds__(256) void k_gather1(
    const unsigned short* __restrict__ xh,
    const int2* __restrict__ rd,
    const int* __restrict__ csr_src,
    unsigned int* __restrict__ meanh)
{
    int lane = threadIdx.x & 63;
    int wv = threadIdx.x >> 6;
    int c = lane & 31;
    int hb = lane & 32;                 // sub-wave base for shfl
    const unsigned* xp = (const unsigned*)xh;   // row = 32 uints

    int node0 = blockIdx.x * 8 + wv * 2 + (hb >> 5);
    for (int row = node0; row < N_NODES; row += gridDim.x * 8) {
        int2 rdv = rd[row];
        int start = rdv.x, dg = rdv.y;
        int end = start + dg;
        float x0 = 0.f, y0 = 0.f, x1 = 0.f, y1 = 0.f;
        float x2 = 0.f, y2 = 0.f, x3 = 0.f, y3 = 0.f;
        float x4 = 0.f, y4 = 0.f, x5 = 0.f, y5 = 0.f;
        float x6 = 0.f, y6 = 0.f, x7 = 0.f, y7 = 0.f;
        for (int eb = start; eb < end; eb += 32) {
            int nv = end - eb; if (nv > 32) nv = 32;
            int sid = (c < nv) ? csr_src[eb + c] : 0;
            int j = 0;
            for (; j + 8 <= nv; j += 8) {
                int s0 = __shfl(sid, hb + j + 0, 64);
                int s1 = __shfl(sid, hb + j + 1, 64);
                int s2 = __shfl(sid, hb + j + 2, 64);
                int s3 = __shfl(sid, hb + j + 3, 64);
                int s4 = __shfl(sid, hb + j + 4, 64);
                int s5 = __shfl(sid, hb + j + 5, 64);
                int s6 = __shfl(sid, hb + j + 6, 64);
                int s7 = __shfl(sid, hb + j + 7, 64);
                unsigned v0 = xp[s0 * 32 + c];
                unsigned v1 = xp[s1 * 32 + c];
                unsigned v2 = xp[s2 * 32 + c];
                unsigned v3 = xp[s3 * 32 + c];
                unsigned v4 = xp[s4 * 32 + c];
                unsigned v5 = xp[s5 * 32 + c];
                unsigned v6 = xp[s6 * 32 + c];
                unsigned v7 = xp[s7 * 32 + c];
                x0 += bflo(v0); y0 += bfhi(v0);
                x1 += bflo(v1); y1 += bfhi(v1);
                x2 += bflo(v2); y2 += bfhi(v2);
                x3 += bflo(v3); y3 += bfhi(v3);
                x4 += bflo(v4); y4 += bfhi(v4);
                x5 += bflo(v5); y5 += bfhi(v5);
                x6 += bflo(v6); y6 += bfhi(v6);
                x7 += bflo(v7); y7 += bfhi(v7);
            }
            for (; j + 4 <= nv; j += 4) {
                int s0 = __shfl(sid, hb + j + 0, 64);
                int s1 = __shfl(sid, hb + j + 1, 64);
                int s2 = __shfl(sid, hb + j + 2, 64);
                int s3 = __shfl(sid, hb + j + 3, 64);
                unsigned v0 = xp[s0 * 32 + c];
                unsigned v1 = xp[s1 * 32 + c];
                unsigned v2 = xp[s2 * 32 + c];
                unsigned v3 = xp[s3 * 32 + c];
                x0 += bflo(v0); y0 += bfhi(v0);
                x1 += bflo(v1); y1 += bfhi(v1);
                x2 += bflo(v2); y2 += bfhi(v2);
                x3 += bflo(v3); y3 += bfhi(v3);
            }
            for (; j < nv; ++j) {
                int s = __shfl(sid, hb + j, 64);
                unsigned v = xp[s * 32 + c];
                x0 += bflo(v); y0 += bfhi(v);
            }
        }
        float rdeg = 1.0f / fmaxf((float)dg, 1.0f);
        float fx = (((x0 + x1) + (x2 + x3)) + ((x4 + x5) + (x6 + x7))) * rdeg;
        float fy = (((y0 + y1) + (y2 + y3)) + ((y4 + y5) + (y6 + y7))) * rdeg;
        __builtin_nontemporal_store(
            (unsigned)f2bf(fx) | ((unsigned)f2bf(fy) << 16),
            &meanh[(size_t)row * 32 + c]);
    }
}

// MFMA bf16: wave computes 16 rows (layouts verified m89). hr now bf16.
__global__ __launch_bounds__(256) void k_gemm1(
    const unsigned short* __restrict__ xh, const unsigned short* __restrict__ meanh,
    const float* __restrict__ W1l, const float* __restrict__ W1r,
    const float* __restrict__ b1,
    const float* __restrict__ W2l, const float* __restrict__ W2r,
    unsigned short* __restrict__ hWlh, unsigned short* __restrict__ hrh)
{
    __shared__ short sWB1[4 * 4 * 64 * 8];   // 16 KB
    __shared__ short sWB2[2 * 4 * 64 * 8];   //  8 KB
    __shared__ short htile[4][16 * 72];

    int tid = threadIdx.x;
    for (int e = tid; e < 1024; e += 256) {
        int kc = e >> 8, nt = (e >> 6) & 3, ln = e & 63;
        int cc = ln & 15, qd = ln >> 4;
        int n = nt * 16 + cc, k0 = kc * 32 + qd * 8;
        const float* sp = (k0 < 64) ? (W1l + n * 64 + k0) : (W1r + n * 64 + (k0 - 64));
        short* dp = sWB1 + e * 8;
        #pragma unroll
        for (int j = 0; j < 8; ++j) dp[j] = (short)f2bf(sp[j]);
    }
    for (int e = tid; e < 512; e += 256) {
        int kc = e >> 8, nt = (e >> 6) & 3, ln = e & 63;
        int cc = ln & 15, qd = ln >> 4;
        int n = nt * 16 + cc, k0 = kc * 32 + qd * 8;
        const float* sp = (n < 32) ? (W2l + n * 64 + k0) : (W2r + (n - 32) * 64 + k0);
        short* dp = sWB2 + e * 8;
        #pragma unroll
        for (int j = 0; j < 8; ++j) dp[j] = (short)f2bf(sp[j]);
    }
    __syncthreads();

    int lane = tid & 63, w = tid >> 6;
    int c = lane & 15, quad = lane >> 4;
    float bias[4];
    #pragma unroll
    for (int nt = 0; nt < 4; ++nt) bias[nt] = b1[nt * 16 + c];

    const bf16x8* B1 = (const bf16x8*)sWB1;
    const bf16x8* B2 = (const bf16x8*)sWB2;
    short* ht = htile[w];

    for (int r0 = blockIdx.x * 64 + w * 16; r0 < N_NODES; r0 += gridDim.x * 64) {
        int ra = r0 + c; if (ra > N_NODES - 1) ra = N_NODES - 1;
        const bf16x8* mrow = (const bf16x8*)(meanh + (size_t)ra * 64);
        const bf16x8* xrow = (const bf16x8*)(xh + (size_t)ra * 64);
        bf16x8 a0 = mrow[quad];
        bf16x8 a1 = mrow[4 + quad];
        bf16x8 a2 = xrow[quad];
        bf16x8 a3 = xrow[4 + quad];

        f32x4 acc[4];
        #pragma unroll
        for (int nt = 0; nt < 4; ++nt) acc[nt] = (f32x4){0.f, 0.f, 0.f, 0.f};
        #pragma unroll
        for (int nt = 0; nt < 4; ++nt)
            acc[nt] = __builtin_amdgcn_mfma_f32_16x16x32_bf16(a0, B1[(0 * 4 + nt) * 64 + lane], acc[nt], 0, 0, 0);
        #pragma unroll
        for (int nt = 0; nt < 4; ++nt)
            acc[nt] = __builtin_amdgcn_mfma_f32_16x16x32_bf16(a1, B1[(1 * 4 + nt) * 64 + lane], acc[nt], 0, 0, 0);
        #pragma unroll
        for (int nt = 0; nt < 4; ++nt)
            acc[nt] = __builtin_amdgcn_mfma_f32_16x16x32_bf16(a2, B1[(2 * 4 + nt) * 64 + lane], acc[nt], 0, 0, 0);
        #pragma unroll
        for (int nt = 0; nt < 4; ++nt)
            acc[nt] = __builtin_amdgcn_mfma_f32_16x16x32_bf16(a3, B1[(3 * 4 + nt) * 64 + lane], acc[nt], 0, 0, 0);

        #pragma unroll
        for (int nt = 0; nt < 4; ++nt) {
            #pragma unroll
            for (int reg = 0; reg < 4; ++reg) {
                float hv = fmaxf(acc[nt][reg] + bias[nt], 0.0f);
                ht[(quad * 4 + reg) * 72 + nt * 16 + c] = (short)f2bf(hv);
            }
        }
        bf16x8 h0 = *(const bf16x8*)(ht + c * 72 + 0  + quad * 8);
        bf16x8 h1 = *(const bf16x8*)(ht + c * 72 + 32 + quad * 8);

        f32x4 acc2[4];
        #pragma unroll
        for (int nt = 0; nt < 4; ++nt) acc2[nt] = (f32x4){0.f, 0.f, 0.f, 0.f};
        #pragma unroll
        for (int nt = 0; nt < 4; ++nt)
            acc2[nt] = __builtin_amdgcn_mfma_f32_16x16x32_bf16(h0, B2[(0 * 4 + nt) * 64 + lane], acc2[nt], 0, 0, 0);
        #pragma unroll
        for (int nt = 0; nt < 4; ++nt)
            acc2[nt] = __builtin_amdgcn_mfma_f32_16x16x32_bf16(h1, B2[(1 * 4 + nt) * 64 + lane], acc2[nt], 0, 0, 0);

        #pragma unroll
        for (int nt = 0; nt < 4; ++nt) {
            #pragma unroll
            for (int reg = 0; reg < 4; ++reg) {
                int row = r0 + quad * 4 + reg;
                if (row < N_NODES) {
                    unsigned short q = f2bf(acc2[nt][reg]);
                    if (nt < 2)
                        __builtin_nontemporal_store(q, &hWlh[(size_t)row * 32 + nt * 16 + c]);
                    else
                        __builtin_nontemporal_store(q, &hrh[(size_t)row * 32 + (nt - 2) * 16 + c]);
                }
            }
        }
    }
}

// Quarter-wave per node, 8 streams -> 32 row-loads in flight per wave.
__global__ __launch_bounds__(256) void k_l2(
    const unsigned short* __restrict__ hWlh, const unsigned short* __restrict__ hrh,
    const int2* __restrict__ rd,
    const int* __restrict__ csr_src,
    const float* __restrict__ b2, float* __restrict__ out)
{
    int lane = threadIdx.x & 63;
    int wv = threadIdx.x >> 6;
    int c = lane & 15;
    int qb = lane & 48;
    const unsigned* hp  = (const unsigned*)hWlh;   // row = 16 uints
    const unsigned* hrp = (const unsigned*)hrh;    // row = 16 uints
    float2 b2v = ((const float2*)b2)[c];

    int node0 = blockIdx.x * 16 + wv * 4 + (qb >> 4);
    for (int row = node0; row < N_NODES; row += gridDim.x * 16) {
        int2 rdv = rd[row];
        int start = rdv.x, dg = rdv.y;
        int end = start + dg;
        float x0 = 0.f, y0 = 0.f, x1 = 0.f, y1 = 0.f;
        float x2 = 0.f, y2 = 0.f, x3 = 0.f, y3 = 0.f;
        float x4 = 0.f, y4 = 0.f, x5 = 0.f, y5 = 0.f;
        float x6 = 0.f, y6 = 0.f, x7 = 0.f, y7 = 0.f;
        for (int eb = start; eb < end; eb += 16) {
            int nv = end - eb; if (nv > 16) nv = 16;
            int sid = (c < nv) ? csr_src[eb + c] : 0;
            int j = 0;
            for (; j + 8 <= nv; j += 8) {
                int s0 = __shfl(sid, qb + j + 0, 64);
                int s1 = __shfl(sid, qb + j + 1, 64);
                int s2 = __shfl(sid, qb + j + 2, 64);
                int s3 = __shfl(sid, qb + j + 3, 64);
                int s4 = __shfl(sid, qb + j + 4, 64);
                int s5 = __shfl(sid, qb + j + 5, 64);
                int s6 = __shfl(sid, qb + j + 6, 64);
                int s7 = __shfl(sid, qb + j + 7, 64);
                unsigned v0 = hp[s0 * 16 + c];
                unsigned v1 = hp[s1 * 16 + c];
                unsigned v2 = hp[s2 * 16 + c];
                unsigned v3 = hp[s3 * 16 + c];
                unsigned v4 = hp[s4 * 16 + c];
                unsigned v5 = hp[s5 * 16 + c];
                unsigned v6 = hp[s6 * 16 + c];
                unsigned v7 = hp[s7 * 16 + c];
                x0 += bflo(v0); y0 += bfhi(v0);
                x1 += bflo(v1); y1 += bfhi(v1);
                x2 += bflo(v2); y2 += bfhi(v2);
                x3 += bflo(v3); y3 += bfhi(v3);
                x4 += bflo(v4); y4 += bfhi(v4);
                x5 += bflo(v5); y5 += bfhi(v5);
                x6 += bflo(v6); y6 += bfhi(v6);
                x7 += bflo(v7); y7 += bfhi(v7);
            }
            for (; j + 4 <= nv; j += 4) {
                int s0 = __shfl(sid, qb + j + 0, 64);
                int s1 = __shfl(sid, qb + j + 1, 64);
                int s2 = __shfl(sid, qb + j + 2, 64);
                int s3 = __shfl(sid, qb + j + 3, 64);
                unsigned v0 = hp[s0 * 16 + c];
                unsigned v1 = hp[s1 * 16 + c];
                unsigned v2 = hp[s2 * 16 + c];
                unsigned v3 = hp[s3 * 16 + c];
                x0 += bflo(v0); y0 += bfhi(v0);
                x1 += bflo(v1); y1 += bfhi(v1);
                x2 += bflo(v2); y2 += bfhi(v2);
                x3 += bflo(v3); y3 += bfhi(v3);
            }
            for (; j < nv; ++j) {
                int s = __shfl(sid, qb + j, 64);
                unsigned v = hp[s * 16 + c];
                x0 += bflo(v); y0 += bfhi(v);
            }
        }
        float fx = ((x0 + x1) + (x2 + x3)) + ((x4 + x5) + (x6 + x7));
        float fy = ((y0 + y1) + (y2 + y3)) + ((y4 + y5) + (y6 + y7));
        float rdeg = 1.0f / fmaxf((float)dg, 1.0f);
        unsigned hru = hrp[(size_t)row * 16 + c];
        float ox = fmaf(fx, rdeg, bflo(hru) + b2v.x);
        float oy = fmaf(fy, rdeg, bfhi(hru) + b2v.y);
        __builtin_nontemporal_store(ox, &out[(size_t)row * 32 + 2 * c]);
        __builtin_nontemporal_store(oy, &out[(size_t)row * 32 + 2 * c + 1]);
    }
}

extern "C" void kernel_launch(void* const* d_in, const int* in_sizes, int n_in,
                              void* d_out, int out_size, void* d_ws, size_t ws_size,
                              hipStream_t stream) {
    const float* x   = (const float*)d_in[0];
    const int*   ei  = (const int*)d_in[1];
    const float* W1l = (const float*)d_in[2];
    const float* W1r = (const float*)d_in[3];
    const float* b1  = (const float*)d_in[4];
    const float* W2l = (const float*)d_in[5];
    const float* W2r = (const float*)d_in[6];
    const float* b2  = (const float*)d_in[7];
    float* out = (float*)d_out;

    const int* src = ei;
    const int* dst = ei + N_EDGES;

    char* w = (char*)d_ws;
    int2* rd     = (int2*)w;  w += sizeof(int2) * (N_NODES + 4);
    int* pcnt    = (int*)w;   w += sizeof(int) * (PREP_NB * BUCKETS);
    int* csr_src = (int*)w;   w += sizeof(int) * (BUCKETS * CSRCAP);   // 6.4 MB
    int* ebuf    = (int*)w;   w += sizeof(int) * ((size_t)BUCKETS * BSTRIDE); // 25.6 MB
    unsigned short* xh    = (unsigned short*)w; w += sizeof(short) * (size_t)N_NODES * 64;
    unsigned int*   meanh = (unsigned int*)w;   w += sizeof(int)   * (size_t)N_NODES * 32;
    unsigned short* hWlh  = (unsigned short*)w; w += sizeof(short) * (size_t)N_NODES * 32;
    unsigned short* hrh   = (unsigned short*)w; /* + 6.4 MB; total ~71 MB */

    k_prep<<<PREP_NB, 256, 0, stream>>>(x, xh, src, dst, ebuf, pcnt);
    k_phb<<<BUCKETS, 256, 0, stream>>>(ebuf, pcnt, rd, csr_src);
    k_gather1<<<4096, 256, 0, stream>>>(xh, rd, csr_src, meanh);
    k_gemm1<<<(N_NODES + 63) / 64, 256, 0, stream>>>(
        xh, (const unsigned short*)meanh, W1l, W1r, b1, W2l, W2r, hWlh, hrh);
    k_l2<<<4096, 256, 0, stream>>>(hWlh, hrh, rd, csr_src, b2, out);
}

// Round 12
// 201.063 us; speedup vs baseline: 1.2015x; 1.2015x over previous
//
#include <hip/hip_runtime.h>

#define N_NODES 100000
#define N_EDGES 1250000
#define D_IN 64
#define D_H 64
#define D_OUT 32

#define BUCKETS 196            // ceil(100000 / 512)
#define GRP 512                // nodes per bucket (dst >> 9)
#define PREP_NB 512            // blocks in k_prep
#define PREP_CH 2442           // ceil(N_EDGES / PREP_NB) edges per block
#define SCAP 48                // slack slots per (block,bucket); mean 12.5, +10 sigma
#define BSTRIDE (PREP_NB*SCAP) // ints per bucket region in ebuf = 24576
#define CSRCAP 8192            // csr slots per bucket; mean 6378, +22 sigma (fixed graph)

typedef __attribute__((ext_vector_type(8))) short bf16x8;
typedef __attribute__((ext_vector_type(4))) float f32x4;

__device__ __forceinline__ unsigned short f2bf(float f) {
    unsigned u = __float_as_uint(f);
    u = (u + 0x7fffu + ((u >> 16) & 1u)) >> 16;   // RNE
    return (unsigned short)u;
}
__device__ __forceinline__ float bfhi(unsigned v) { return __uint_as_float(v & 0xffff0000u); }
__device__ __forceinline__ float bflo(unsigned v) { return __uint_as_float(v << 16); }

// ---------------------------------------------------------------------------
// 5-dispatch pipeline (R10 geometry restored; R11 lesson: every intermediate
// is consumed by the next kernel -- L2 residency is a feature, NEVER use
// nontemporal stores here; they tripled k_prep via write-through).
// Kept from R11: hr in bf16 (saves 12.8MB round-trip gemm1->l2).
//   k_prep   : x->bf16 xh + bucket edges into fixed slack regions (LDS only)
//   k_phb    : per bucket: slack->LDS, hist+scan -> rd(rstart,deg), csr_src
//   k_gather1: half-wave per node, 8-stream ILP, mean(xh[src]) -> meanh
//   k_gemm1  : MFMA bf16 layer1+ReLU+W2 premultiplies -> hWlh, hrh
//   k_l2     : quarter-wave per node, 8-stream ILP, mean(hWl[src])+hr+b2 -> out
// ---------------------------------------------------------------------------

__global__ __launch_bounds__(256) void k_prep(const float* __restrict__ x,
                                              unsigned short* __restrict__ xh,
                                              const int* __restrict__ src,
                                              const int* __restrict__ dst,
                                              int* __restrict__ ebuf,
                                              int* __restrict__ pcnt) {
    __shared__ int ofs[BUCKETS];
    int t = threadIdx.x, b = blockIdx.x;
    for (int i = t; i < BUCKETS; i += 256) ofs[i] = 0;
    __syncthreads();

    const int TOT = N_NODES * 64 / 4;
    for (int i = b * 256 + t; i < TOT; i += PREP_NB * 256) {
        float4 v = *(const float4*)(x + (size_t)i * 4);
        uint2 u;
        u.x = (unsigned)f2bf(v.x) | ((unsigned)f2bf(v.y) << 16);
        u.y = (unsigned)f2bf(v.z) | ((unsigned)f2bf(v.w) << 16);
        *(uint2*)(xh + (size_t)i * 4) = u;
    }

    int e0 = b * PREP_CH;
    int e1 = e0 + PREP_CH; if (e1 > N_EDGES) e1 = N_EDGES;
    for (int e = e0 + t; e < e1; e += 256) {
        int s = src[e], d = dst[e];
        if ((unsigned)d >= N_NODES) continue;
        int sv = ((unsigned)s < N_NODES) ? s : 0;
        int bk = d >> 9;
        int r = atomicAdd(&ofs[bk], 1);
        if (r < SCAP) ebuf[bk * BSTRIDE + b * SCAP + r] = ((d & 511) << 17) | sv;
    }
    __syncthreads();
    for (int i = t; i < BUCKETS; i += 256) {
        int v = ofs[i]; if (v > SCAP) v = SCAP;
        pcnt[b * BUCKETS + i] = v;        // [blk][bucket]: coalesced writes
    }
}

// One block per bucket. rd[node] = (rstart, deg) packed.
__global__ __launch_bounds__(256) void k_phb(const int* __restrict__ ebuf,
                                             const int* __restrict__ pcnt,
                                             int2* __restrict__ rd,
                                             int* __restrict__ csr_src) {
    __shared__ int sedge[CSRCAP];   // 32 KB
    __shared__ int pc[PREP_NB];
    __shared__ int cnt[GRP];
    __shared__ int part[256];
    int b = blockIdx.x, t = threadIdx.x;

    int c0 = pcnt[(2 * t) * BUCKETS + b];
    int c1 = pcnt[(2 * t + 1) * BUCKETS + b];
    int s = c0 + c1;
    part[t] = s;
    __syncthreads();
    for (int off = 1; off < 256; off <<= 1) {
        int u = (t >= off) ? part[t - off] : 0;
        __syncthreads();
        part[t] += u;
        __syncthreads();
    }
    int run = part[t] - s;
    pc[2 * t] = run;
    pc[2 * t + 1] = run + c0;
    int n = part[255]; if (n > CSRCAP) n = CSRCAP;
    for (int i = t; i < GRP; i += 256) cnt[i] = 0;
    {
        const int* sp = ebuf + b * BSTRIDE + (2 * t) * SCAP;
        int base = pc[2 * t];
        for (int j = 0; j < c0; ++j) if (base + j < CSRCAP) sedge[base + j] = sp[j];
        sp += SCAP;
        base = pc[2 * t + 1];
        for (int j = 0; j < c1; ++j) if (base + j < CSRCAP) sedge[base + j] = sp[j];
    }
    __syncthreads();
    for (int i = t; i < n; i += 256) atomicAdd(&cnt[sedge[i] >> 17], 1);
    __syncthreads();
    int d0 = cnt[2 * t], d1 = cnt[2 * t + 1];
    int s2 = d0 + d1;
    part[t] = s2;
    __syncthreads();
    for (int off = 1; off < 256; off <<= 1) {
        int u = (t >= off) ? part[t - off] : 0;
        __syncthreads();
        part[t] += u;
        __syncthreads();
    }
    int g0 = b * CSRCAP + part[t] - s2;
    int node0 = b * GRP + 2 * t;
    if (node0 + 1 < N_NODES) {
        *(int4*)(rd + node0) = make_int4(g0, d0, g0 + d0, d1);  // 16B aligned (node0 even)
    } else if (node0 < N_NODES) {
        rd[node0] = make_int2(g0, d0);
    }
    __syncthreads();
    cnt[2 * t] = g0;
    cnt[2 * t + 1] = g0 + d0;
    __syncthreads();
    for (int i = t; i < n; i += 256) {
        int v = sedge[i];
        int pos = atomicAdd(&cnt[v >> 17], 1);
        csr_src[pos] = v & 0x1FFFF;
    }
}

// Half-wave per node (lanes c=0..31 cover the 128B bf16 row as bfloat162).
// 8 accumulator streams -> 16 row-loads in flight per wave.
__global__ __launch_bounds__(256) void k_gather1(
    const unsigned short* __restrict__ xh,
    const int2* __restrict__ rd,
    const int* __restrict__ csr_src,
    unsigned int* __restrict__ meanh)
{
    int lane = threadIdx.x & 63;
    int wv = threadIdx.x >> 6;
    int c = lane & 31;
    int hb = lane & 32;                 // sub-wave base for shfl
    const unsigned* xp = (const unsigned*)xh;   // row = 32 uints

    int node0 = blockIdx.x * 8 + wv * 2 + (hb >> 5);
    for (int row = node0; row < N_NODES; row += gridDim.x * 8) {
        int2 rdv = rd[row];
        int start = rdv.x, dg = rdv.y;
        int end = start + dg;
        float x0 = 0.f, y0 = 0.f, x1 = 0.f, y1 = 0.f;
        float x2 = 0.f, y2 = 0.f, x3 = 0.f, y3 = 0.f;
        float x4 = 0.f, y4 = 0.f, x5 = 0.f, y5 = 0.f;
        float x6 = 0.f, y6 = 0.f, x7 = 0.f, y7 = 0.f;
        for (int eb = start; eb < end; eb += 32) {
            int nv = end - eb; if (nv > 32) nv = 32;
            int sid = (c < nv) ? csr_src[eb + c] : 0;
            int j = 0;
            for (; j + 8 <= nv; j += 8) {
                int s0 = __shfl(sid, hb + j + 0, 64);
                int s1 = __shfl(sid, hb + j + 1, 64);
                int s2 = __shfl(sid, hb + j + 2, 64);
                int s3 = __shfl(sid, hb + j + 3, 64);
                int s4 = __shfl(sid, hb + j + 4, 64);
                int s5 = __shfl(sid, hb + j + 5, 64);
                int s6 = __shfl(sid, hb + j + 6, 64);
                int s7 = __shfl(sid, hb + j + 7, 64);
                unsigned v0 = xp[s0 * 32 + c];
                unsigned v1 = xp[s1 * 32 + c];
                unsigned v2 = xp[s2 * 32 + c];
                unsigned v3 = xp[s3 * 32 + c];
                unsigned v4 = xp[s4 * 32 + c];
                unsigned v5 = xp[s5 * 32 + c];
                unsigned v6 = xp[s6 * 32 + c];
                unsigned v7 = xp[s7 * 32 + c];
                x0 += bflo(v0); y0 += bfhi(v0);
                x1 += bflo(v1); y1 += bfhi(v1);
                x2 += bflo(v2); y2 += bfhi(v2);
                x3 += bflo(v3); y3 += bfhi(v3);
                x4 += bflo(v4); y4 += bfhi(v4);
                x5 += bflo(v5); y5 += bfhi(v5);
                x6 += bflo(v6); y6 += bfhi(v6);
                x7 += bflo(v7); y7 += bfhi(v7);
            }
            for (; j + 4 <= nv; j += 4) {
                int s0 = __shfl(sid, hb + j + 0, 64);
                int s1 = __shfl(sid, hb + j + 1, 64);
                int s2 = __shfl(sid, hb + j + 2, 64);
                int s3 = __shfl(sid, hb + j + 3, 64);
                unsigned v0 = xp[s0 * 32 + c];
                unsigned v1 = xp[s1 * 32 + c];
                unsigned v2 = xp[s2 * 32 + c];
                unsigned v3 = xp[s3 * 32 + c];
                x0 += bflo(v0); y0 += bfhi(v0);
                x1 += bflo(v1); y1 += bfhi(v1);
                x2 += bflo(v2); y2 += bfhi(v2);
                x3 += bflo(v3); y3 += bfhi(v3);
            }
            for (; j < nv; ++j) {
                int s = __shfl(sid, hb + j, 64);
                unsigned v = xp[s * 32 + c];
                x0 += bflo(v); y0 += bfhi(v);
            }
        }
        float rdeg = 1.0f / fmaxf((float)dg, 1.0f);
        float fx = (((x0 + x1) + (x2 + x3)) + ((x4 + x5) + (x6 + x7))) * rdeg;
        float fy = (((y0 + y1) + (y2 + y3)) + ((y4 + y5) + (y6 + y7))) * rdeg;
        meanh[(size_t)row * 32 + c] = (unsigned)f2bf(fx) | ((unsigned)f2bf(fy) << 16);
    }
}

// MFMA bf16: wave computes 16 rows (layouts verified m89). hr in bf16.
__global__ __launch_bounds__(256) void k_gemm1(
    const unsigned short* __restrict__ xh, const unsigned short* __restrict__ meanh,
    const float* __restrict__ W1l, const float* __restrict__ W1r,
    const float* __restrict__ b1,
    const float* __restrict__ W2l, const float* __restrict__ W2r,
    unsigned short* __restrict__ hWlh, unsigned short* __restrict__ hrh)
{
    __shared__ short sWB1[4 * 4 * 64 * 8];   // 16 KB
    __shared__ short sWB2[2 * 4 * 64 * 8];   //  8 KB
    __shared__ short htile[4][16 * 72];

    int tid = threadIdx.x;
    for (int e = tid; e < 1024; e += 256) {
        int kc = e >> 8, nt = (e >> 6) & 3, ln = e & 63;
        int cc = ln & 15, qd = ln >> 4;
        int n = nt * 16 + cc, k0 = kc * 32 + qd * 8;
        const float* sp = (k0 < 64) ? (W1l + n * 64 + k0) : (W1r + n * 64 + (k0 - 64));
        short* dp = sWB1 + e * 8;
        #pragma unroll
        for (int j = 0; j < 8; ++j) dp[j] = (short)f2bf(sp[j]);
    }
    for (int e = tid; e < 512; e += 256) {
        int kc = e >> 8, nt = (e >> 6) & 3, ln = e & 63;
        int cc = ln & 15, qd = ln >> 4;
        int n = nt * 16 + cc, k0 = kc * 32 + qd * 8;
        const float* sp = (n < 32) ? (W2l + n * 64 + k0) : (W2r + (n - 32) * 64 + k0);
        short* dp = sWB2 + e * 8;
        #pragma unroll
        for (int j = 0; j < 8; ++j) dp[j] = (short)f2bf(sp[j]);
    }
    __syncthreads();

    int lane = tid & 63, w = tid >> 6;
    int c = lane & 15, quad = lane >> 4;
    float bias[4];
    #pragma unroll
    for (int nt = 0; nt < 4; ++nt) bias[nt] = b1[nt * 16 + c];

    const bf16x8* B1 = (const bf16x8*)sWB1;
    const bf16x8* B2 = (const bf16x8*)sWB2;
    short* ht = htile[w];

    for (int r0 = blockIdx.x * 64 + w * 16; r0 < N_NODES; r0 += gridDim.x * 64) {
        int ra = r0 + c; if (ra > N_NODES - 1) ra = N_NODES - 1;
        const bf16x8* mrow = (const bf16x8*)(meanh + (size_t)ra * 64);
        const bf16x8* xrow = (const bf16x8*)(xh + (size_t)ra * 64);
        bf16x8 a0 = mrow[quad];
        bf16x8 a1 = mrow[4 + quad];
        bf16x8 a2 = xrow[quad];
        bf16x8 a3 = xrow[4 + quad];

        f32x4 acc[4];
        #pragma unroll
        for (int nt = 0; nt < 4; ++nt) acc[nt] = (f32x4){0.f, 0.f, 0.f, 0.f};
        #pragma unroll
        for (int nt = 0; nt < 4; ++nt)
            acc[nt] = __builtin_amdgcn_mfma_f32_16x16x32_bf16(a0, B1[(0 * 4 + nt) * 64 + lane], acc[nt], 0, 0, 0);
        #pragma unroll
        for (int nt = 0; nt < 4; ++nt)
            acc[nt] = __builtin_amdgcn_mfma_f32_16x16x32_bf16(a1, B1[(1 * 4 + nt) * 64 + lane], acc[nt], 0, 0, 0);
        #pragma unroll
        for (int nt = 0; nt < 4; ++nt)
            acc[nt] = __builtin_amdgcn_mfma_f32_16x16x32_bf16(a2, B1[(2 * 4 + nt) * 64 + lane], acc[nt], 0, 0, 0);
        #pragma unroll
        for (int nt = 0; nt < 4; ++nt)
            acc[nt] = __builtin_amdgcn_mfma_f32_16x16x32_bf16(a3, B1[(3 * 4 + nt) * 64 + lane], acc[nt], 0, 0, 0);

        #pragma unroll
        for (int nt = 0; nt < 4; ++nt) {
            #pragma unroll
            for (int reg = 0; reg < 4; ++reg) {
                float hv = fmaxf(acc[nt][reg] + bias[nt], 0.0f);
                ht[(quad * 4 + reg) * 72 + nt * 16 + c] = (short)f2bf(hv);
            }
        }
        bf16x8 h0 = *(const bf16x8*)(ht + c * 72 + 0  + quad * 8);
        bf16x8 h1 = *(const bf16x8*)(ht + c * 72 + 32 + quad * 8);

        f32x4 acc2[4];
        #pragma unroll
        for (int nt = 0; nt < 4; ++nt) acc2[nt] = (f32x4){0.f, 0.f, 0.f, 0.f};
        #pragma unroll
        for (int nt = 0; nt < 4; ++nt)
            acc2[nt] = __builtin_amdgcn_mfma_f32_16x16x32_bf16(h0, B2[(0 * 4 + nt) * 64 + lane], acc2[nt], 0, 0, 0);
        #pragma unroll
        for (int nt = 0; nt < 4; ++nt)
            acc2[nt] = __builtin_amdgcn_mfma_f32_16x16x32_bf16(h1, B2[(1 * 4 + nt) * 64 + lane], acc2[nt], 0, 0, 0);

        #pragma unroll
        for (int nt = 0; nt < 4; ++nt) {
            #pragma unroll
            for (int reg = 0; reg < 4; ++reg) {
                int row = r0 + quad * 4 + reg;
                if (row < N_NODES) {
                    unsigned short q = f2bf(acc2[nt][reg]);
                    if (nt < 2) hWlh[(size_t)row * 32 + nt * 16 + c] = q;
                    else        hrh [(size_t)row * 32 + (nt - 2) * 16 + c] = q;
                }
            }
        }
    }
}

// Quarter-wave per node, 8 streams -> 32 row-loads in flight per wave.
__global__ __launch_bounds__(256) void k_l2(
    const unsigned short* __restrict__ hWlh, const unsigned short* __restrict__ hrh,
    const int2* __restrict__ rd,
    const int* __restrict__ csr_src,
    const float* __restrict__ b2, float* __restrict__ out)
{
    int lane = threadIdx.x & 63;
    int wv = threadIdx.x >> 6;
    int c = lane & 15;
    int qb = lane & 48;
    const unsigned* hp  = (const unsigned*)hWlh;   // row = 16 uints
    const unsigned* hrp = (const unsigned*)hrh;    // row = 16 uints
    float2 b2v = ((const float2*)b2)[c];

    int node0 = blockIdx.x * 16 + wv * 4 + (qb >> 4);
    for (int row = node0; row < N_NODES; row += gridDim.x * 16) {
        int2 rdv = rd[row];
        int start = rdv.x, dg = rdv.y;
        int end = start + dg;
        float x0 = 0.f, y0 = 0.f, x1 = 0.f, y1 = 0.f;
        float x2 = 0.f, y2 = 0.f, x3 = 0.f, y3 = 0.f;
        float x4 = 0.f, y4 = 0.f, x5 = 0.f, y5 = 0.f;
        float x6 = 0.f, y6 = 0.f, x7 = 0.f, y7 = 0.f;
        for (int eb = start; eb < end; eb += 16) {
            int nv = end - eb; if (nv > 16) nv = 16;
            int sid = (c < nv) ? csr_src[eb + c] : 0;
            int j = 0;
            for (; j + 8 <= nv; j += 8) {
                int s0 = __shfl(sid, qb + j + 0, 64);
                int s1 = __shfl(sid, qb + j + 1, 64);
                int s2 = __shfl(sid, qb + j + 2, 64);
                int s3 = __shfl(sid, qb + j + 3, 64);
                int s4 = __shfl(sid, qb + j + 4, 64);
                int s5 = __shfl(sid, qb + j + 5, 64);
                int s6 = __shfl(sid, qb + j + 6, 64);
                int s7 = __shfl(sid, qb + j + 7, 64);
                unsigned v0 = hp[s0 * 16 + c];
                unsigned v1 = hp[s1 * 16 + c];
                unsigned v2 = hp[s2 * 16 + c];
                unsigned v3 = hp[s3 * 16 + c];
                unsigned v4 = hp[s4 * 16 + c];
                unsigned v5 = hp[s5 * 16 + c];
                unsigned v6 = hp[s6 * 16 + c];
                unsigned v7 = hp[s7 * 16 + c];
                x0 += bflo(v0); y0 += bfhi(v0);
                x1 += bflo(v1); y1 += bfhi(v1);
                x2 += bflo(v2); y2 += bfhi(v2);
                x3 += bflo(v3); y3 += bfhi(v3);
                x4 += bflo(v4); y4 += bfhi(v4);
                x5 += bflo(v5); y5 += bfhi(v5);
                x6 += bflo(v6); y6 += bfhi(v6);
                x7 += bflo(v7); y7 += bfhi(v7);
            }
            for (; j + 4 <= nv; j += 4) {
                int s0 = __shfl(sid, qb + j + 0, 64);
                int s1 = __shfl(sid, qb + j + 1, 64);
                int s2 = __shfl(sid, qb + j + 2, 64);
                int s3 = __shfl(sid, qb + j + 3, 64);
                unsigned v0 = hp[s0 * 16 + c];
                unsigned v1 = hp[s1 * 16 + c];
                unsigned v2 = hp[s2 * 16 + c];
                unsigned v3 = hp[s3 * 16 + c];
                x0 += bflo(v0); y0 += bfhi(v0);
                x1 += bflo(v1); y1 += bfhi(v1);
                x2 += bflo(v2); y2 += bfhi(v2);
                x3 += bflo(v3); y3 += bfhi(v3);
            }
            for (; j < nv; ++j) {
                int s = __shfl(sid, qb + j, 64);
                unsigned v = hp[s * 16 + c];
                x0 += bflo(v); y0 += bfhi(v);
            }
        }
        float fx = ((x0 + x1) + (x2 + x3)) + ((x4 + x5) + (x6 + x7));
        float fy = ((y0 + y1) + (y2 + y3)) + ((y4 + y5) + (y6 + y7));
        float rdeg = 1.0f / fmaxf((float)dg, 1.0f);
        unsigned hru = hrp[(size_t)row * 16 + c];
        float2 o;
        o.x = fmaf(fx, rdeg, bflo(hru) + b2v.x);
        o.y = fmaf(fy, rdeg, bfhi(hru) + b2v.y);
        ((float2*)out)[(size_t)row * 16 + c] = o;
    }
}

extern "C" void kernel_launch(void* const* d_in, const int* in_sizes, int n_in,
                              void* d_out, int out_size, void* d_ws, size_t ws_size,
                              hipStream_t stream) {
    const float* x   = (const float*)d_in[0];
    const int*   ei  = (const int*)d_in[1];
    const float* W1l = (const float*)d_in[2];
    const float* W1r = (const float*)d_in[3];
    const float* b1  = (const float*)d_in[4];
    const float* W2l = (const float*)d_in[5];
    const float* W2r = (const float*)d_in[6];
    const float* b2  = (const float*)d_in[7];
    float* out = (float*)d_out;

    const int* src = ei;
    const int* dst = ei + N_EDGES;

    char* w = (char*)d_ws;
    int2* rd     = (int2*)w;  w += sizeof(int2) * (N_NODES + 4);
    int* pcnt    = (int*)w;   w += sizeof(int) * (PREP_NB * BUCKETS);
    int* csr_src = (int*)w;   w += sizeof(int) * (BUCKETS * CSRCAP);   // 6.4 MB
    int* ebuf    = (int*)w;   w += sizeof(int) * ((size_t)BUCKETS * BSTRIDE); // 19.3 MB
    unsigned short* xh    = (unsigned short*)w; w += sizeof(short) * (size_t)N_NODES * 64;
    unsigned int*   meanh = (unsigned int*)w;   w += sizeof(int)   * (size_t)N_NODES * 32;
    unsigned short* hWlh  = (unsigned short*)w; w += sizeof(short) * (size_t)N_NODES * 32;
    unsigned short* hrh   = (unsigned short*)w; /* + 6.4 MB; total ~64 MB */

    k_prep<<<PREP_NB, 256, 0, stream>>>(x, xh, src, dst, ebuf, pcnt);
    k_phb<<<BUCKETS, 256, 0, stream>>>(ebuf, pcnt, rd, csr_src);
    k_gather1<<<4096, 256, 0, stream>>>(xh, rd, csr_src, meanh);
    k_gemm1<<<(N_NODES + 63) / 64, 256, 0, stream>>>(
        xh, (const unsigned short*)meanh, W1l, W1r, b1, W2l, W2r, hWlh, hrh);
    k_l2<<<4096, 256, 0, stream>>>(hWlh, hrh, rd, csr_src, b2, out);
}